// Round 4
// baseline (973.309 us; speedup 1.0000x reference)
//
#include <hip/hip_runtime.h>
#include <hip/hip_bf16.h>
#include <math.h>

// Problem constants (from reference setup_inputs)
#define Bq   16
#define Sq   1024
#define Hq   1024
#define Oq   256
#define Lq   4
#define NHq  8
#define DHq  128
#define Mq   (Bq*Sq)      // 16384 rows
#define HHq  (Hq*Hq)      // 1048576
#define NCc  32           // scan chunks
#define CTc  32           // timesteps per chunk

typedef __bf16 bf16x8 __attribute__((ext_vector_type(8)));
typedef float  f32x4  __attribute__((ext_vector_type(4)));

__device__ __forceinline__ float bf2f(unsigned int u) {
    union { unsigned int i; float f; } x; x.i = u << 16; return x.f;
}
__device__ __forceinline__ unsigned short f2bf(float f) {
    union { float f; unsigned int i; } x; x.f = f;
    unsigned int r = x.i + 0x7fffu + ((x.i >> 16) & 1u);   // RNE
    return (unsigned short)(r >> 16);
}
__device__ __forceinline__ float sigm(float x) { return 1.f / (1.f + __expf(-x)); }

__device__ __forceinline__ void gl2lds16(const unsigned short* g, unsigned short* l) {
    __builtin_amdgcn_global_load_lds((const __attribute__((address_space(1))) void*)g,
                                     (__attribute__((address_space(3))) void*)l, 16, 0, 0);
}

// ---------------- fp32 -> bf16 convert ----------------
__global__ void cvt_kernel(const float* __restrict__ src, unsigned short* __restrict__ dst, int n) {
    int i = blockIdx.x * 256 + threadIdx.x;
    if (i < n) dst[i] = f2bf(src[i]);
}

// ---------------- fused weight convert: Wcat[l][f;i;h][H][H] ----------------
__global__ void cvtW_kernel(const float* __restrict__ Wf, const float* __restrict__ Wi,
                            const float* __restrict__ Wh, unsigned short* __restrict__ Wcat) {
    int i = blockIdx.x * 256 + threadIdx.x;     // L*3*HH
    int l = (i >> 20) / 3;
    int r = i - l * 3 * HHq;
    int g = r >> 20; int j = r & (HHq - 1);
    const float* s = (g == 0) ? Wf : (g == 1) ? Wi : Wh;
    Wcat[i] = f2bf(s[(size_t)l * HHq + j]);
}

// ---------------- assemble per-layer [bf;bi;bh] bias (L x 3072) ----------------
__global__ void bias3_kernel(const float* __restrict__ bf_, const float* __restrict__ bi_,
                             const float* __restrict__ bh_, float* __restrict__ out) {
    int i = blockIdx.x * 256 + threadIdx.x;          // L*3H = 12288
    int l = i / (3*Hq); int r = i % (3*Hq); int g = r >> 10; int j = r & (Hq-1);
    const float* s = (g == 0) ? bf_ : (g == 1) ? bi_ : bh_;
    out[i] = s[l*Hq + j];
}

// ---------------- FUSED 3-gate GEMM + gate math ----------------
// R4: the kernel is LDS-READ-BANDWIDTH bound. Model: MfmaUtil =
// 4.85*Mw*3Nw/(512*(Mw+3Nw)) at ~128B/cyc LDS read BW -> 36.4% for the old
// 64x(32x3) wave tile; measured 35.5% in BOTH 1-block and 2-block structures.
// Fix: 1M x 4N wave decomposition, wave tile 128 rows x (32 x 3 gates):
// 8 A-frags + 6 W-frags -> 48 MFMA per 14 reads (ratio 52% predicted).
// acc = 3x8x2 frags = 192 VGPR (fits 2 waves/SIMD).
// Sync: dbuf-2 + counted vmcnt(8) + bare post-compute s_barrier (no drain).
// The round-0 cost was the vmcnt(0) DRAIN, not the barrier; post-barrier
// needs no waitcnt (all ds_reads consumed by MFMAs before it). Slot = A 8KB +
// W 24KB = 32KB, dbuf 64KB -> 2 blocks/CU.
// Safety: STAGE(t+1) at iter t overwrites slot (t-1)&1, released by ALL waves
// at post-barrier(t-1); vmcnt(8) retires exactly tile t's 8 loads (t+1's 8 in
// flight); pre-barrier -> every wave's tile-t loads landed before any read.
// Staging/fragment swizzle pattern identical to the verified zero-conflict
// mapping (only row counts change); accumulation order unchanged (32 x BK=32).
__global__ __launch_bounds__(256, 2)
void gemm_gate_kernel(const unsigned short* __restrict__ A, const unsigned short* __restrict__ Wl,
                      const float* __restrict__ bias3, unsigned short* __restrict__ FPo,
                      unsigned short* __restrict__ ADDo)
{
    const int K = Hq;
    __shared__ unsigned short lds[2 * 16384];   // 64 KB: 2 slots x (A 4096 + W 12288 shorts)
    const int tid  = threadIdx.x;

    // XCD swizzle: 1024 blocks; per XCD 16 bm x 8 cb, cb fastest.
    const int lid = blockIdx.x;               // 1024 blocks
    const int xcd = lid & 7;
    const int s   = lid >> 3;                 // 0..127
    const int bm  = xcd * 16 + (s >> 3);      // 0..127
    const int cb  = s & 7;                    // channel block (128 channels)

    const int wid  = tid >> 6, lane = tid & 63;
    const int wn   = wid * 32;                // 0/32/64/96 within each gate
    const int l15  = lane & 15, quad = lane >> 4;

    const unsigned short* Ag = A + (size_t)(bm*128) * K;

    // --- staging offsets (verified swizzle: key=(lane>>3)&3, phys chunk lane&3) ---
    const int lr   = lane >> 2;               // 0..15 row within 16-row issue
    const int gc   = (lane & 3) ^ ((lane >> 3) & 3);
    // A: wave w stages rows [w*32, w*32+32) in 2 issues of 16 rows
    int offA[2], ldsA[2];
    #pragma unroll
    for (int q = 0; q < 2; ++q) {
        int ra = wid*32 + q*16 + lr;
        offA[q] = ra * K + gc*8;
        ldsA[q] = (wid*32 + q*16) * 32;
    }
    // W: wave w stages W-LDS rows [w*96, w*96+96) in 6 issues of 16 rows.
    // W-LDS row rw -> gate g=rw>>7, row-in-gate nr=rw&127 (issues never cross gates:
    // issue starts are multiples of 16, gate boundaries multiples of 128).
    int offW[6], ldsW[6];
    #pragma unroll
    for (int q = 0; q < 6; ++q) {
        int rw = wid*96 + q*16 + lr;
        int g  = rw >> 7;
        int nr = rw & 127;
        offW[q] = g * HHq + (cb*128 + nr) * K + gc*8;
        ldsW[q] = 4096 + (wid*96 + q*16) * 32;
    }

    // fragment read swizzle: phys chunk = quad ^ ((l15>>1)&3)
    const int crd = quad ^ ((l15 >> 1) & 3);

    f32x4 acc[3][8][2] = {};                  // 192 VGPR accumulator

    auto STAGE = [&](int kt, int slot) {
        const int kof = kt << 5;
        unsigned short* Sb = &lds[slot * 16384];
        #pragma unroll
        for (int q = 0; q < 2; ++q) gl2lds16(Ag + offA[q] + kof, Sb + ldsA[q]);
        #pragma unroll
        for (int q = 0; q < 6; ++q) gl2lds16(Wl + offW[q] + kof, Sb + ldsW[q]);
    };

    auto COMPUTE = [&](int slot) {
        const unsigned short* Sa = &lds[slot * 16384];
        const unsigned short* Sw = Sa + 4096;
        bf16x8 af[8];
        #pragma unroll
        for (int t = 0; t < 8; ++t)
            af[t] = *(const bf16x8*)&Sa[(t*16 + l15)*32 + crd*8];
        __builtin_amdgcn_s_setprio(1);
        #pragma unroll
        for (int g = 0; g < 3; ++g) {
            bf16x8 wf[2];
            #pragma unroll
            for (int t = 0; t < 2; ++t)
                wf[t] = *(const bf16x8*)&Sw[(g*128 + wn + t*16 + l15)*32 + crd*8];
            #pragma unroll
            for (int tm = 0; tm < 8; ++tm)
                #pragma unroll
                for (int tn = 0; tn < 2; ++tn)
                    acc[g][tm][tn] = __builtin_amdgcn_mfma_f32_16x16x32_bf16(af[tm], wf[tn], acc[g][tm][tn], 0, 0, 0);
        }
        __builtin_amdgcn_s_setprio(0);
    };

    const int niter = K >> 5;                 // 32 K-tiles

    STAGE(0, 0);
    for (int t = 0; t < niter - 1; ++t) {
        STAGE(t + 1, (t + 1) & 1);
        asm volatile("s_waitcnt vmcnt(8) lgkmcnt(0)" ::: "memory");
        __builtin_amdgcn_s_barrier();
        asm volatile("" ::: "memory");
        COMPUTE(t & 1);
        asm volatile("" ::: "memory");
        __builtin_amdgcn_s_barrier();         // release slot (no drain needed)
        asm volatile("" ::: "memory");
    }
    asm volatile("s_waitcnt vmcnt(0) lgkmcnt(0)" ::: "memory");
    __builtin_amdgcn_s_barrier();
    asm volatile("" ::: "memory");
    COMPUTE((niter - 1) & 1);

    // epilogue: gate math + bf16 FP/ADD write (C layout: row=quad*4+r, col=l15)
    #pragma unroll
    for (int tm = 0; tm < 8; ++tm) {
        int row0 = bm*128 + tm*16 + quad*4;
        #pragma unroll
        for (int tn = 0; tn < 2; ++tn) {
            int col = cb*128 + wn + tn*16 + l15;
            float bf_ = bias3[col], bi_ = bias3[Hq + col], bh_ = bias3[2*Hq + col];
            #pragma unroll
            for (int r = 0; r < 4; ++r) {
                float f  = sigm(acc[0][tm][tn][r] + bf_);
                float i  = sigm(acc[1][tm][tn][r] + bi_);
                float ht = acc[2][tm][tn][r] + bh_;
                float rd = 1.f / (f + i);
                size_t off = (size_t)(row0 + r) * Hq + col;
                FPo[off]  = f2bf(f * rd);
                ADDo[off] = f2bf(i * rd * ht);
            }
        }
    }
}

// ---------------- plain bf16 GEMM (used for KV projection) ----------------
// R4: same LDS-read-BW reasoning. Wave tile 128 rows x 64 cols (1M x 4N):
// 8 A-frags + 4 W-frags -> 32 MFMA per 12 reads (ratio 41% vs old 30%).
// Block 128 x 256, slot = A 8KB + W 16KB = 24KB, dbuf 48KB -> 2 blocks/CU.
// 6 loads/thread/tile -> vmcnt(6). acc 8x4 = 128 VGPR.
__global__ __launch_bounds__(256, 2)
void gemm_bt_kernel(const unsigned short* __restrict__ A, const unsigned short* __restrict__ W,
                    const float* __restrict__ bias, unsigned short* __restrict__ C,
                    int N, int K, int nbn)
{
    __shared__ unsigned short lds[2 * 12288];   // 48 KB: 2 slots x (A 4096 + W 8192 shorts)
    const int tid  = threadIdx.x;

    const int lid = blockIdx.x;
    const int xcd = lid & 7;
    const int s   = lid >> 3;
    const int bm  = xcd * 16 + s / nbn;
    const int bn  = s % nbn;

    const int wid  = tid >> 6, lane = tid & 63;
    const int wn   = wid * 64;                // 0/64/128/192
    const int l15  = lane & 15, quad = lane >> 4;

    const unsigned short* Ag = A + (size_t)(bm*128) * K;

    const int lr   = lane >> 2;
    const int gc   = (lane & 3) ^ ((lane >> 3) & 3);
    int offA[2], ldsA[2];
    #pragma unroll
    for (int q = 0; q < 2; ++q) {
        int ra = wid*32 + q*16 + lr;
        offA[q] = ra * K + gc*8;
        ldsA[q] = (wid*32 + q*16) * 32;
    }
    // W: 256 rows staged; wave w stages rows [w*64, w*64+64) in 4 issues of 16.
    int offW[4], ldsW[4];
    #pragma unroll
    for (int q = 0; q < 4; ++q) {
        int rw = wid*64 + q*16 + lr;
        offW[q] = (bn*256 + rw) * K + gc*8;
        ldsW[q] = 4096 + (wid*64 + q*16) * 32;
    }

    const int crd = quad ^ ((l15 >> 1) & 3);

    f32x4 acc[8][4] = {};                     // 128 VGPR accumulator

    auto STAGE = [&](int kt, int slot) {
        const int kof = kt << 5;
        unsigned short* Sb = &lds[slot * 12288];
        #pragma unroll
        for (int q = 0; q < 2; ++q) gl2lds16(Ag + offA[q] + kof, Sb + ldsA[q]);
        #pragma unroll
        for (int q = 0; q < 4; ++q) gl2lds16(W + offW[q] + kof, Sb + ldsW[q]);
    };

    auto COMPUTE = [&](int slot) {
        const unsigned short* Sa = &lds[slot * 12288];
        const unsigned short* Sw = Sa + 4096;
        bf16x8 af[8], wf[4];
        #pragma unroll
        for (int t = 0; t < 8; ++t)
            af[t] = *(const bf16x8*)&Sa[(t*16 + l15)*32 + crd*8];
        #pragma unroll
        for (int t = 0; t < 4; ++t)
            wf[t] = *(const bf16x8*)&Sw[(wn + t*16 + l15)*32 + crd*8];
        __builtin_amdgcn_s_setprio(1);
        #pragma unroll
        for (int tm = 0; tm < 8; ++tm)
            #pragma unroll
            for (int tn = 0; tn < 4; ++tn)
                acc[tm][tn] = __builtin_amdgcn_mfma_f32_16x16x32_bf16(af[tm], wf[tn], acc[tm][tn], 0, 0, 0);
        __builtin_amdgcn_s_setprio(0);
    };

    const int niter = K >> 5;

    STAGE(0, 0);
    for (int it = 0; it < niter - 1; ++it) {
        STAGE(it + 1, (it + 1) & 1);
        asm volatile("s_waitcnt vmcnt(6) lgkmcnt(0)" ::: "memory");
        __builtin_amdgcn_s_barrier();
        asm volatile("" ::: "memory");
        COMPUTE(it & 1);
        asm volatile("" ::: "memory");
        __builtin_amdgcn_s_barrier();
        asm volatile("" ::: "memory");
    }
    asm volatile("s_waitcnt vmcnt(0) lgkmcnt(0)" ::: "memory");
    __builtin_amdgcn_s_barrier();
    asm volatile("" ::: "memory");
    COMPUTE((niter - 1) & 1);

    #pragma unroll
    for (int tm = 0; tm < 8; ++tm) {
        int row0 = bm*128 + tm*16 + quad*4;
        #pragma unroll
        for (int tn = 0; tn < 4; ++tn) {
            int col = bn*256 + wn + tn*16 + l15;
            float bv = bias[col];
            #pragma unroll
            for (int r = 0; r < 4; ++r)
                C[(size_t)(row0 + r) * N + col] = f2bf(acc[tm][tn][r] + bv);
        }
    }
}

// ---------------- chunked scan over precomputed FP/ADD ----------------
// Pass A: per (b,chunk,j-pair): P = prod fp, Asum = local scan from h=0.
__global__ __launch_bounds__(256)
void scan_sum_kernel(const unsigned short* __restrict__ FP, const unsigned short* __restrict__ AD,
                     float* __restrict__ Ps, float* __restrict__ Asum) {
    int bid = blockIdx.x;                    // B*NC*2 = 1024
    int tid = threadIdx.x;
    int b = bid >> 6; int r = bid & 63; int chunk = r >> 1; int jb = r & 1;
    int j = jb*512 + tid*2;
    size_t base = ((size_t)(b*Sq + chunk*CTc)) * Hq + j;
    float P0 = 1.f, P1 = 1.f, A0 = 0.f, A1 = 0.f;
    for (int s = 0; s < CTc; ++s) {
        size_t ro = base + (size_t)s * Hq;
        unsigned int uf = *(const unsigned int*)(FP + ro);
        unsigned int ua = *(const unsigned int*)(AD + ro);
        float fp0 = bf2f(uf & 0xffffu), fp1 = bf2f(uf >> 16);
        float ad0 = bf2f(ua & 0xffffu), ad1 = bf2f(ua >> 16);
        P0 *= fp0; A0 = fp0 * A0 + ad0;
        P1 *= fp1; A1 = fp1 * A1 + ad1;
    }
    int oi = (b*NCc + chunk)*Hq + j;
    Ps[oi] = P0; Ps[oi+1] = P1;
    Asum[oi] = A0; Asum[oi+1] = A1;
}

// Pass B: chunk-level prefix. h entering chunk c stored to Hb.
__global__ void scan_base_kernel(const float* __restrict__ Ps, const float* __restrict__ Asum,
                                 float* __restrict__ Hb) {
    int t = blockIdx.x * 256 + threadIdx.x;  // B*H = 16384
    int b = t >> 10, j = t & 1023;
    float h = 0.f;
    for (int c = 0; c < NCc; ++c) {
        int idx = (b*NCc + c)*Hq + j;
        Hb[idx] = h;
        h = Ps[idx] * h + Asum[idx];
    }
}

// Pass C: re-read FP/ADD, scan with correct init, write bf16 h.
__global__ __launch_bounds__(256)
void scan_out_kernel(const unsigned short* __restrict__ FP, const unsigned short* __restrict__ AD,
                     const float* __restrict__ Hb, unsigned short* __restrict__ Ho) {
    int bid = blockIdx.x;                    // B*NC*2 = 1024
    int tid = threadIdx.x;
    int b = bid >> 6; int r = bid & 63; int chunk = r >> 1; int jb = r & 1;
    int j = jb*512 + tid*2;
    size_t base = ((size_t)(b*Sq + chunk*CTc)) * Hq + j;
    int oi = (b*NCc + chunk)*Hq + j;
    float h0 = Hb[oi], h1 = Hb[oi+1];
    for (int s = 0; s < CTc; ++s) {
        size_t ro = base + (size_t)s * Hq;
        unsigned int uf = *(const unsigned int*)(FP + ro);
        unsigned int ua = *(const unsigned int*)(AD + ro);
        h0 = bf2f(uf & 0xffffu) * h0 + bf2f(ua & 0xffffu);
        h1 = bf2f(uf >> 16)     * h1 + bf2f(ua >> 16);
        unsigned int packed = (unsigned int)f2bf(h0) | ((unsigned int)f2bf(h1) << 16);
        *(unsigned int*)(Ho + ro) = packed;
    }
}

// ---------------- extract last-position activations as fp32 ----------------
__global__ void xlast_kernel(const unsigned short* __restrict__ act, float* __restrict__ xl) {
    int i = blockIdx.x * 256 + threadIdx.x;  // B*H
    int b = i >> 10, j = i & 1023;
    xl[i] = bf2f((unsigned int)act[((size_t)(b*Sq + Sq-1)) * Hq + j]);
}

// ---------------- wave-per-row GEMV: out[b,n] = W[n,:].x[b,:] + bias[n] (+resid[b,n]) ----------------
__global__ __launch_bounds__(256)
void gemv_kernel(const float* __restrict__ W, const float* __restrict__ xv,
                 const float* __restrict__ bias, const float* __restrict__ resid,
                 float* __restrict__ out, int N) {
    int b = blockIdx.x;
    int w = threadIdx.x >> 6, lane = threadIdx.x & 63;
    int n = blockIdx.y*4 + w;
    __shared__ float xs[Hq];
    *(float4*)&xs[threadIdx.x*4] = *(const float4*)&xv[(size_t)b*Hq + threadIdx.x*4];
    __syncthreads();
    const float4* wr = (const float4*)(W + (size_t)n * Hq);
    float a = 0.f;
    #pragma unroll
    for (int c = 0; c < 4; ++c) {
        float4 wv = wr[c*64 + lane];
        float4 x4 = *(const float4*)&xs[c*256 + lane*4];
        a += wv.x*x4.x + wv.y*x4.y + wv.z*x4.z + wv.w*x4.w;
    }
    #pragma unroll
    for (int st = 32; st > 0; st >>= 1) a += __shfl_xor(a, st, 64);
    if (lane == 0) out[(size_t)b*N + n] = a + bias[n] + (resid ? resid[(size_t)b*Hq + n] : 0.f);
}

// ---------------- attention for the single last-position query ----------------
__global__ __launch_bounds__(1024)
void attn_kernel(const unsigned short* __restrict__ KV,
                 const float* __restrict__ q, float* __restrict__ o) {
    int b = blockIdx.x >> 3, nh = blockIdx.x & 7;
    int tid = threadIdx.x;
    __shared__ float qs[DHq];
    __shared__ float p[Sq];
    __shared__ float redw[16];
    __shared__ float red2[16*DHq];
    if (tid < DHq) qs[tid] = q[b*Hq + nh*DHq + tid] * 0.08838834764831845f;
    __syncthreads();

    const int g = tid >> 4, l = tid & 15;
    const unsigned short* Kb = KV + (size_t)b*Sq*2048 + nh*DHq;
    float lmax = -1e30f;
    #pragma unroll 4
    for (int it = 0; it < 16; ++it) {
        int s = it*64 + g;
        union { uint4 v; unsigned short u[8]; } kk;
        kk.v = *(const uint4*)(Kb + (size_t)s*2048 + l*8);
        float a = 0.f;
        #pragma unroll
        for (int j = 0; j < 8; ++j) a += bf2f((unsigned int)kk.u[j]) * qs[l*8 + j];
        a += __shfl_xor(a, 1, 16);
        a += __shfl_xor(a, 2, 16);
        a += __shfl_xor(a, 4, 16);
        a += __shfl_xor(a, 8, 16);
        if (l == 0) p[s] = a;
        lmax = fmaxf(lmax, a);
    }
    #pragma unroll
    for (int st = 32; st > 0; st >>= 1) lmax = fmaxf(lmax, __shfl_xor(lmax, st, 64));
    if ((tid & 63) == 0) redw[tid >> 6] = lmax;
    __syncthreads();
    float mx = redw[0];
    #pragma unroll
    for (int i = 1; i < 16; ++i) mx = fmaxf(mx, redw[i]);

    float e = __expf(p[tid] - mx);
    float ls = e;
    #pragma unroll
    for (int st = 32; st > 0; st >>= 1) ls += __shfl_xor(ls, st, 64);
    __syncthreads();
    p[tid] = e;
    if ((tid & 63) == 0) redw[tid >> 6] = ls;
    __syncthreads();
    float ssum = 0.f;
    #pragma unroll
    for (int i = 0; i < 16; ++i) ssum += redw[i];
    float inv = 1.f / ssum;

    int d2 = (tid & 63) * 2, sb = tid >> 6;
    const unsigned short* Vb = KV + (size_t)b*Sq*2048 + 1024 + nh*DHq + d2;
    float a0 = 0.f, a1 = 0.f;
    for (int s = sb*64; s < sb*64 + 64; ++s) {
        unsigned int vv = *(const unsigned int*)(Vb + (size_t)s*2048);
        float pw = p[s];
        a0 += pw * bf2f(vv & 0xffffu);
        a1 += pw * bf2f(vv >> 16);
    }
    red2[sb*DHq + d2] = a0;
    red2[sb*DHq + d2 + 1] = a1;
    __syncthreads();
    if (tid < DHq) {
        float a = 0.f;
        #pragma unroll
        for (int i = 0; i < 16; ++i) a += red2[i*DHq + tid];
        o[b*Hq + nh*DHq + tid] = a * inv;
    }
}

extern "C" void kernel_launch(void* const* d_in, const int* in_sizes, int n_in,
                              void* d_out, int out_size, void* d_ws, size_t ws_size,
                              hipStream_t stream) {
    const float* x        = (const float*)d_in[0];
    const float* Wf       = (const float*)d_in[1];
    const float* bfv      = (const float*)d_in[2];
    const float* Wi       = (const float*)d_in[3];
    const float* biv      = (const float*)d_in[4];
    const float* Wh       = (const float*)d_in[5];
    const float* bhv      = (const float*)d_in[6];
    const float* in_proj_w= (const float*)d_in[7];
    const float* in_proj_b= (const float*)d_in[8];
    const float* out_w    = (const float*)d_in[9];
    const float* out_b    = (const float*)d_in[10];
    const float* fc_w     = (const float*)d_in[11];
    const float* fc_b     = (const float*)d_in[12];
    float* outp = (float*)d_out;

    // workspace carve (~160 MB)
    char* p = (char*)d_ws;
    auto alloc = [&](size_t bytes) -> void* {
        void* r = (void*)p; p += (bytes + 255) & ~(size_t)255; return r;
    };
    unsigned short* Wcat = (unsigned short*)alloc((size_t)Lq*3*HHq*2);  // 24 MB
    unsigned short* Wkv  = (unsigned short*)alloc((size_t)2048*Hq*2);   //  4 MB
    float*          Bias3= (float*)alloc((size_t)Lq*3*Hq*4);            // 48 KB
    unsigned short* actA = (unsigned short*)alloc((size_t)Mq*Hq*2);     // 32 MB
    unsigned short* actB = (unsigned short*)alloc((size_t)Mq*Hq*2);     // 32 MB
    unsigned short* FPg  = (unsigned short*)alloc((size_t)Mq*Hq*2);     // 32 MB
    unsigned short* ADDg = (unsigned short*)alloc((size_t)Mq*Hq*2);     // 32 MB (contiguous after FPg)
    float* Ps   = (float*)alloc((size_t)Bq*NCc*Hq*4);                   //  2 MB
    float* Asum = (float*)alloc((size_t)Bq*NCc*Hq*4);                   //  2 MB
    float* Hb   = (float*)alloc((size_t)Bq*NCc*Hq*4);                   //  2 MB
    unsigned short* KV = FPg;  // alias: 64 MB (FPg+ADDg), used only after layers done
    float* xl   = (float*)alloc((size_t)Bq*Hq*4);
    float* qbuf = (float*)alloc((size_t)Bq*Hq*4);
    float* obuf = (float*)alloc((size_t)Bq*Hq*4);
    float* rbuf = (float*)alloc((size_t)Bq*Hq*4);

    // --- conversions ---
    cvt_kernel<<<Mq*Hq/256, 256, 0, stream>>>(x, actA, Mq*Hq);
    cvtW_kernel<<<Lq*3*HHq/256, 256, 0, stream>>>(Wf, Wi, Wh, Wcat);
    cvt_kernel<<<2048*Hq/256, 256, 0, stream>>>(in_proj_w + (size_t)Hq*Hq, Wkv, 2048*Hq);
    bias3_kernel<<<(Lq*3*Hq)/256, 256, 0, stream>>>(bfv, biv, bhv, Bias3);

    // --- minLSTM layers ---
    unsigned short* cur = actA;
    unsigned short* nxt = actB;
    for (int l = 0; l < Lq; ++l) {
        gemm_gate_kernel<<<(Mq/128)*(Hq/128), 256, 0, stream>>>(
            cur, Wcat + (size_t)l*3*HHq, Bias3 + l*3*Hq, FPg, ADDg);
        scan_sum_kernel<<<Bq*NCc*2, 256, 0, stream>>>(FPg, ADDg, Ps, Asum);
        scan_base_kernel<<<Bq*Hq/256, 256, 0, stream>>>(Ps, Asum, Hb);
        scan_out_kernel<<<Bq*NCc*2, 256, 0, stream>>>(FPg, ADDg, Hb, nxt);
        unsigned short* t = cur; cur = nxt; nxt = t;
    }

    // --- attention (only last-position query matters) ---
    gemm_bt_kernel<<<(Mq/128)*(2048/256), 256, 0, stream>>>(
        cur, Wkv, in_proj_b + Hq, KV, 2048, Hq, 2048/256);
    xlast_kernel<<<Bq*Hq/256, 256, 0, stream>>>(cur, xl);
    gemv_kernel<<<dim3(Bq, Hq/4), 256, 0, stream>>>(in_proj_w, xl, in_proj_b, nullptr, qbuf, Hq);
    attn_kernel<<<Bq*NHq, 1024, 0, stream>>>(KV, qbuf, obuf);
    gemv_kernel<<<dim3(Bq, Hq/4), 256, 0, stream>>>(out_w, obuf, out_b, xl, rbuf, Hq);
    gemv_kernel<<<dim3(Bq, Oq/4), 256, 0, stream>>>(fc_w, rbuf, fc_b, nullptr, outp, Oq);
}

// Round 5
// 842.140 us; speedup vs baseline: 1.1558x; 1.1558x over previous
//
#include <hip/hip_runtime.h>
#include <hip/hip_bf16.h>
#include <math.h>

// Problem constants (from reference setup_inputs)
#define Bq   16
#define Sq   1024
#define Hq   1024
#define Oq   256
#define Lq   4
#define NHq  8
#define DHq  128
#define Mq   (Bq*Sq)      // 16384 rows
#define HHq  (Hq*Hq)      // 1048576
#define NCc  32           // scan chunks
#define CTc  32           // timesteps per chunk

typedef __bf16 bf16x8 __attribute__((ext_vector_type(8)));
typedef float  f32x4  __attribute__((ext_vector_type(4)));

__device__ __forceinline__ float bf2f(unsigned int u) {
    union { unsigned int i; float f; } x; x.i = u << 16; return x.f;
}
__device__ __forceinline__ unsigned short f2bf(float f) {
    union { float f; unsigned int i; } x; x.f = f;
    unsigned int r = x.i + 0x7fffu + ((x.i >> 16) & 1u);   // RNE
    return (unsigned short)(r >> 16);
}
__device__ __forceinline__ float sigm(float x) { return 1.f / (1.f + __expf(-x)); }

__device__ __forceinline__ void gl2lds16(const unsigned short* g, unsigned short* l) {
    __builtin_amdgcn_global_load_lds((const __attribute__((address_space(1))) void*)g,
                                     (__attribute__((address_space(3))) void*)l, 16, 0, 0);
}

// ---------------- fp32 -> bf16 convert ----------------
__global__ void cvt_kernel(const float* __restrict__ src, unsigned short* __restrict__ dst, int n) {
    int i = blockIdx.x * 256 + threadIdx.x;
    if (i < n) dst[i] = f2bf(src[i]);
}

// ---------------- fused weight convert: Wcat[l][f;i;h][H][H] ----------------
__global__ void cvtW_kernel(const float* __restrict__ Wf, const float* __restrict__ Wi,
                            const float* __restrict__ Wh, unsigned short* __restrict__ Wcat) {
    int i = blockIdx.x * 256 + threadIdx.x;     // L*3*HH
    int l = (i >> 20) / 3;
    int r = i - l * 3 * HHq;
    int g = r >> 20; int j = r & (HHq - 1);
    const float* s = (g == 0) ? Wf : (g == 1) ? Wi : Wh;
    Wcat[i] = f2bf(s[(size_t)l * HHq + j]);
}

// ---------------- assemble per-layer [bf;bi;bh] bias (L x 3072) ----------------
__global__ void bias3_kernel(const float* __restrict__ bf_, const float* __restrict__ bi_,
                             const float* __restrict__ bh_, float* __restrict__ out) {
    int i = blockIdx.x * 256 + threadIdx.x;          // L*3H = 12288
    int l = i / (3*Hq); int r = i % (3*Hq); int g = r >> 10; int j = r & (Hq-1);
    const float* s = (g == 0) ? bf_ : (g == 1) ? bi_ : bh_;
    out[i] = s[l*Hq + j];
}

// ---------------- FUSED 3-gate GEMM + gate math ----------------
// R5: big wave tile + PROVEN distance-2 ring. Round-4 post-mortem: dbuf-2
// distance-1 exposed HBM latency (~900cyc, m126) every iter -> 27% util; the
// LDS-ratio thesis was never tested. This round: keep round-3's ring-4 /
// counted-vmcnt / one-barrier structure EXACTLY (vmcnt ladder 10/5/0, slot
// (t+2)&3 two barriers old), and grow the block to 512 thr / 8 waves:
// block 256 rows x 128 ch x 3 gates, wave tile 128 x (32x3) via 2M x 4N.
// Slot = A 16KB + W 24KB = 40KB; ring-4 = 160KB (full LDS pool, 1 block/CU
// -- AITER precedent; rounds 1 vs 3 showed blocks/CU is irrelevant here).
// LDS-BW model (calibrated on r1/r3: ~128 B/cyc/CU effective): 8 waves x
// 14KB = 112KB -> 875 cyc; MFMA 2/SIMD x 48 x 4.85 = 466 cyc -> util ~53%
// (vs 37% predicted / 35.5% measured for the old 64x96 wave tile).
// Staging/fragment swizzle pattern identical (row-block starts stay multiples
// of 16); accumulation order unchanged (32 x BK=32) -> same numerics.
__global__ __launch_bounds__(512, 1)
void gemm_gate_kernel(const unsigned short* __restrict__ A, const unsigned short* __restrict__ Wl,
                      const float* __restrict__ bias3, unsigned short* __restrict__ FPo,
                      unsigned short* __restrict__ ADDo)
{
    const int K = Hq;
    __shared__ unsigned short lds[4 * 20480];   // 160 KB: 4 slots x (A 8192 + W 12288 shorts)
    const int tid  = threadIdx.x;

    // XCD swizzle: 512 blocks; per XCD 8 bm x 8 cb, cb fastest -> A-tile (512KB)
    // shared by 8 consecutive blocks on one XCD.
    const int lid = blockIdx.x;               // 512 blocks
    const int xcd = lid & 7;
    const int s   = lid >> 3;                 // 0..63
    const int bm  = xcd * 8 + (s >> 3);       // 0..63 (256-row blocks)
    const int cb  = s & 7;                    // channel block (128 channels)

    const int wid  = tid >> 6, lane = tid & 63;
    const int wm   = (wid >> 2) * 128;        // 0/128
    const int wn   = (wid & 3) * 32;          // 0/32/64/96 within each gate
    const int l15  = lane & 15, quad = lane >> 4;

    const unsigned short* Ag = A + (size_t)(bm*256) * K;

    // --- staging offsets (verified swizzle: key=(lane>>3)&3, phys chunk lane&3) ---
    const int lr   = lane >> 2;               // 0..15 row within 16-row issue
    const int gc   = (lane & 3) ^ ((lane >> 3) & 3);
    // A: 256 rows; wave w stages rows [w*32, w*32+32) in 2 issues of 16 rows
    int offA[2], ldsA[2];
    #pragma unroll
    for (int q = 0; q < 2; ++q) {
        int ra = wid*32 + q*16 + lr;
        offA[q] = ra * K + gc*8;
        ldsA[q] = (wid*32 + q*16) * 32;
    }
    // W: 384 LDS rows (3 gates x 128); wave w stages [w*48, w*48+48) in 3 issues
    // of 16. Row rw -> gate g=rw>>7, row-in-gate nr=rw&127 (issue starts are
    // multiples of 16, gate boundaries multiples of 128 -> never cross gates).
    int offW[3], ldsW[3];
    #pragma unroll
    for (int q = 0; q < 3; ++q) {
        int rw = wid*48 + q*16 + lr;
        int g  = rw >> 7;
        int nr = rw & 127;
        offW[q] = g * HHq + (cb*128 + nr) * K + gc*8;
        ldsW[q] = 8192 + (wid*48 + q*16) * 32;
    }

    // fragment read swizzle: phys chunk = quad ^ ((l15>>1)&3)
    const int crd = quad ^ ((l15 >> 1) & 3);

    f32x4 acc[3][8][2] = {};                  // 192-reg accumulator (AGPR half of unified file)

    auto STAGE = [&](int kt, int slot) {
        const int kof = kt << 5;
        unsigned short* Sb = &lds[slot * 20480];
        #pragma unroll
        for (int q = 0; q < 2; ++q) gl2lds16(Ag + offA[q] + kof, Sb + ldsA[q]);
        #pragma unroll
        for (int q = 0; q < 3; ++q) gl2lds16(Wl + offW[q] + kof, Sb + ldsW[q]);
    };

    auto COMPUTE = [&](int slot) {
        const unsigned short* Sa = &lds[slot * 20480];
        const unsigned short* Sw = Sa + 8192;
        bf16x8 af[8];
        #pragma unroll
        for (int t = 0; t < 8; ++t)
            af[t] = *(const bf16x8*)&Sa[(wm + t*16 + l15)*32 + crd*8];
        __builtin_amdgcn_s_setprio(1);
        #pragma unroll
        for (int g = 0; g < 3; ++g) {
            bf16x8 wf[2];
            #pragma unroll
            for (int t = 0; t < 2; ++t)
                wf[t] = *(const bf16x8*)&Sw[(g*128 + wn + t*16 + l15)*32 + crd*8];
            #pragma unroll
            for (int tm = 0; tm < 8; ++tm)
                #pragma unroll
                for (int tn = 0; tn < 2; ++tn)
                    acc[g][tm][tn] = __builtin_amdgcn_mfma_f32_16x16x32_bf16(af[tm], wf[tn], acc[g][tm][tn], 0, 0, 0);
        }
        __builtin_amdgcn_s_setprio(0);
    };

    const int niter = K >> 5;                 // 32 K-tiles

    // prologue: tiles 0,1 in flight
    STAGE(0, 0);
    STAGE(1, 1);

    // main loop: counted vmcnt(10) = tiles t+1,t+2 (5 loads each) stay in flight
    for (int t = 0; t < niter - 2; ++t) {
        STAGE(t + 2, (t + 2) & 3);
        asm volatile("s_waitcnt vmcnt(10) lgkmcnt(0)" ::: "memory");
        __builtin_amdgcn_s_barrier();
        asm volatile("" ::: "memory");
        COMPUTE(t & 3);
    }
    // tail: drain 5 -> 0
    asm volatile("s_waitcnt vmcnt(5) lgkmcnt(0)" ::: "memory");
    __builtin_amdgcn_s_barrier();
    asm volatile("" ::: "memory");
    COMPUTE((niter - 2) & 3);
    asm volatile("s_waitcnt vmcnt(0) lgkmcnt(0)" ::: "memory");
    __builtin_amdgcn_s_barrier();
    asm volatile("" ::: "memory");
    COMPUTE((niter - 1) & 3);

    // epilogue: gate math + bf16 FP/ADD write (C layout: row=quad*4+r, col=l15)
    #pragma unroll
    for (int tm = 0; tm < 8; ++tm) {
        int row0 = bm*256 + wm + tm*16 + quad*4;
        #pragma unroll
        for (int tn = 0; tn < 2; ++tn) {
            int col = cb*128 + wn + tn*16 + l15;
            float bf_ = bias3[col], bi_ = bias3[Hq + col], bh_ = bias3[2*Hq + col];
            #pragma unroll
            for (int r = 0; r < 4; ++r) {
                float f  = sigm(acc[0][tm][tn][r] + bf_);
                float i  = sigm(acc[1][tm][tn][r] + bi_);
                float ht = acc[2][tm][tn][r] + bh_;
                float rd = 1.f / (f + i);
                size_t off = (size_t)(row0 + r) * Hq + col;
                FPo[off]  = f2bf(f * rd);
                ADDo[off] = f2bf(i * rd * ht);
            }
        }
    }
}

// ---------------- plain bf16 GEMM (used for KV projection) ----------------
// Round-3-verified ring-4 counted-vmcnt pipeline (slot = A 8KB + W 8KB =
// 16KB, ring = 64KB -> 2 blocks/CU; 4 loads/tile/thread -> vmcnt(8)).
__global__ __launch_bounds__(256, 2)
void gemm_bt_kernel(const unsigned short* __restrict__ A, const unsigned short* __restrict__ W,
                    const float* __restrict__ bias, unsigned short* __restrict__ C,
                    int N, int K, int nbn)
{
    __shared__ unsigned short lds[4 * 8192];    // 64 KB: 4 slots x (A 4096 + W 4096 shorts)
    const int tid  = threadIdx.x;

    const int lid = blockIdx.x;
    const int xcd = lid & 7;
    const int s   = lid >> 3;
    const int bm  = xcd * 16 + s / nbn;
    const int bn  = s % nbn;

    const int wid  = tid >> 6, lane = tid & 63;
    const int wm   = (wid >> 1) * 64, wn = (wid & 1) * 64;
    const int l15  = lane & 15, quad = lane >> 4;

    const unsigned short* Ag = A + (size_t)(bm*128) * K;
    const unsigned short* Wg = W + (size_t)(bn*128) * K;

    const int r0   = wid*32 + (lane >> 2);
    const int cst  = (lane & 3) ^ ((r0 >> 1) & 3);
    const int g0   = r0 * K + cst*8;
    const int g1   = (r0 + 16) * K + cst*8;
    const int lofs0 = wid*1024;
    const int lofs1 = wid*1024 + 512;

    const int crd = quad ^ ((l15 >> 1) & 3);

    f32x4 acc[4][4] = {};

    auto STAGE = [&](int kt, int slot) {
        const int kof = kt << 5;
        unsigned short* Sb = &lds[slot * 8192];
        gl2lds16(Ag + g0 + kof, Sb + lofs0);
        gl2lds16(Ag + g1 + kof, Sb + lofs1);
        gl2lds16(Wg + g0 + kof, Sb + 4096 + lofs0);
        gl2lds16(Wg + g1 + kof, Sb + 4096 + lofs1);
    };

    auto COMPUTE = [&](int slot) {
        const unsigned short* Sa = &lds[slot * 8192];
        const unsigned short* Sw = Sa + 4096;
        bf16x8 af[4], wf[4];
        #pragma unroll
        for (int t = 0; t < 4; ++t) {
            af[t] = *(const bf16x8*)&Sa[(wm + t*16 + l15)*32 + crd*8];
            wf[t] = *(const bf16x8*)&Sw[(wn + t*16 + l15)*32 + crd*8];
        }
        __builtin_amdgcn_s_setprio(1);
        #pragma unroll
        for (int tm = 0; tm < 4; ++tm)
            #pragma unroll
            for (int tn = 0; tn < 4; ++tn)
                acc[tm][tn] = __builtin_amdgcn_mfma_f32_16x16x32_bf16(af[tm], wf[tn], acc[tm][tn], 0, 0, 0);
        __builtin_amdgcn_s_setprio(0);
    };

    const int niter = K >> 5;

    STAGE(0, 0);
    STAGE(1, 1);

    for (int it = 0; it < niter - 2; ++it) {
        STAGE(it + 2, (it + 2) & 3);
        asm volatile("s_waitcnt vmcnt(8) lgkmcnt(0)" ::: "memory");
        __builtin_amdgcn_s_barrier();
        asm volatile("" ::: "memory");
        COMPUTE(it & 3);
    }
    asm volatile("s_waitcnt vmcnt(4) lgkmcnt(0)" ::: "memory");
    __builtin_amdgcn_s_barrier();
    asm volatile("" ::: "memory");
    COMPUTE((niter - 2) & 3);
    asm volatile("s_waitcnt vmcnt(0) lgkmcnt(0)" ::: "memory");
    __builtin_amdgcn_s_barrier();
    asm volatile("" ::: "memory");
    COMPUTE((niter - 1) & 3);

    #pragma unroll
    for (int tm = 0; tm < 4; ++tm) {
        int row0 = bm*128 + wm + tm*16 + quad*4;
        #pragma unroll
        for (int tn = 0; tn < 4; ++tn) {
            int col = bn*128 + wn + tn*16 + l15;
            float bv = bias[col];
            #pragma unroll
            for (int r = 0; r < 4; ++r)
                C[(size_t)(row0 + r) * N + col] = f2bf(acc[tm][tn][r] + bv);
        }
    }
}

// ---------------- chunked scan over precomputed FP/ADD ----------------
// Pass A: per (b,chunk,j-pair): P = prod fp, Asum = local scan from h=0.
__global__ __launch_bounds__(256)
void scan_sum_kernel(const unsigned short* __restrict__ FP, const unsigned short* __restrict__ AD,
                     float* __restrict__ Ps, float* __restrict__ Asum) {
    int bid = blockIdx.x;                    // B*NC*2 = 1024
    int tid = threadIdx.x;
    int b = bid >> 6; int r = bid & 63; int chunk = r >> 1; int jb = r & 1;
    int j = jb*512 + tid*2;
    size_t base = ((size_t)(b*Sq + chunk*CTc)) * Hq + j;
    float P0 = 1.f, P1 = 1.f, A0 = 0.f, A1 = 0.f;
    for (int s = 0; s < CTc; ++s) {
        size_t ro = base + (size_t)s * Hq;
        unsigned int uf = *(const unsigned int*)(FP + ro);
        unsigned int ua = *(const unsigned int*)(AD + ro);
        float fp0 = bf2f(uf & 0xffffu), fp1 = bf2f(uf >> 16);
        float ad0 = bf2f(ua & 0xffffu), ad1 = bf2f(ua >> 16);
        P0 *= fp0; A0 = fp0 * A0 + ad0;
        P1 *= fp1; A1 = fp1 * A1 + ad1;
    }
    int oi = (b*NCc + chunk)*Hq + j;
    Ps[oi] = P0; Ps[oi+1] = P1;
    Asum[oi] = A0; Asum[oi+1] = A1;
}

// Pass B: chunk-level prefix. h entering chunk c stored to Hb.
__global__ void scan_base_kernel(const float* __restrict__ Ps, const float* __restrict__ Asum,
                                 float* __restrict__ Hb) {
    int t = blockIdx.x * 256 + threadIdx.x;  // B*H = 16384
    int b = t >> 10, j = t & 1023;
    float h = 0.f;
    for (int c = 0; c < NCc; ++c) {
        int idx = (b*NCc + c)*Hq + j;
        Hb[idx] = h;
        h = Ps[idx] * h + Asum[idx];
    }
}

// Pass C: re-read FP/ADD, scan with correct init, write bf16 h.
__global__ __launch_bounds__(256)
void scan_out_kernel(const unsigned short* __restrict__ FP, const unsigned short* __restrict__ AD,
                     const float* __restrict__ Hb, unsigned short* __restrict__ Ho) {
    int bid = blockIdx.x;                    // B*NC*2 = 1024
    int tid = threadIdx.x;
    int b = bid >> 6; int r = bid & 63; int chunk = r >> 1; int jb = r & 1;
    int j = jb*512 + tid*2;
    size_t base = ((size_t)(b*Sq + chunk*CTc)) * Hq + j;
    int oi = (b*NCc + chunk)*Hq + j;
    float h0 = Hb[oi], h1 = Hb[oi+1];
    for (int s = 0; s < CTc; ++s) {
        size_t ro = base + (size_t)s * Hq;
        unsigned int uf = *(const unsigned int*)(FP + ro);
        unsigned int ua = *(const unsigned int*)(AD + ro);
        h0 = bf2f(uf & 0xffffu) * h0 + bf2f(ua & 0xffffu);
        h1 = bf2f(uf >> 16)     * h1 + bf2f(ua >> 16);
        unsigned int packed = (unsigned int)f2bf(h0) | ((unsigned int)f2bf(h1) << 16);
        *(unsigned int*)(Ho + ro) = packed;
    }
}

// ---------------- extract last-position activations as fp32 ----------------
__global__ void xlast_kernel(const unsigned short* __restrict__ act, float* __restrict__ xl) {
    int i = blockIdx.x * 256 + threadIdx.x;  // B*H
    int b = i >> 10, j = i & 1023;
    xl[i] = bf2f((unsigned int)act[((size_t)(b*Sq + Sq-1)) * Hq + j]);
}

// ---------------- wave-per-row GEMV: out[b,n] = W[n,:].x[b,:] + bias[n] (+resid[b,n]) ----------------
__global__ __launch_bounds__(256)
void gemv_kernel(const float* __restrict__ W, const float* __restrict__ xv,
                 const float* __restrict__ bias, const float* __restrict__ resid,
                 float* __restrict__ out, int N) {
    int b = blockIdx.x;
    int w = threadIdx.x >> 6, lane = threadIdx.x & 63;
    int n = blockIdx.y*4 + w;
    __shared__ float xs[Hq];
    *(float4*)&xs[threadIdx.x*4] = *(const float4*)&xv[(size_t)b*Hq + threadIdx.x*4];
    __syncthreads();
    const float4* wr = (const float4*)(W + (size_t)n * Hq);
    float a = 0.f;
    #pragma unroll
    for (int c = 0; c < 4; ++c) {
        float4 wv = wr[c*64 + lane];
        float4 x4 = *(const float4*)&xs[c*256 + lane*4];
        a += wv.x*x4.x + wv.y*x4.y + wv.z*x4.z + wv.w*x4.w;
    }
    #pragma unroll
    for (int st = 32; st > 0; st >>= 1) a += __shfl_xor(a, st, 64);
    if (lane == 0) out[(size_t)b*N + n] = a + bias[n] + (resid ? resid[(size_t)b*Hq + n] : 0.f);
}

// ---------------- attention for the single last-position query ----------------
__global__ __launch_bounds__(1024)
void attn_kernel(const unsigned short* __restrict__ KV,
                 const float* __restrict__ q, float* __restrict__ o) {
    int b = blockIdx.x >> 3, nh = blockIdx.x & 7;
    int tid = threadIdx.x;
    __shared__ float qs[DHq];
    __shared__ float p[Sq];
    __shared__ float redw[16];
    __shared__ float red2[16*DHq];
    if (tid < DHq) qs[tid] = q[b*Hq + nh*DHq + tid] * 0.08838834764831845f;
    __syncthreads();

    const int g = tid >> 4, l = tid & 15;
    const unsigned short* Kb = KV + (size_t)b*Sq*2048 + nh*DHq;
    float lmax = -1e30f;
    #pragma unroll 4
    for (int it = 0; it < 16; ++it) {
        int s = it*64 + g;
        union { uint4 v; unsigned short u[8]; } kk;
        kk.v = *(const uint4*)(Kb + (size_t)s*2048 + l*8);
        float a = 0.f;
        #pragma unroll
        for (int j = 0; j < 8; ++j) a += bf2f((unsigned int)kk.u[j]) * qs[l*8 + j];
        a += __shfl_xor(a, 1, 16);
        a += __shfl_xor(a, 2, 16);
        a += __shfl_xor(a, 4, 16);
        a += __shfl_xor(a, 8, 16);
        if (l == 0) p[s] = a;
        lmax = fmaxf(lmax, a);
    }
    #pragma unroll
    for (int st = 32; st > 0; st >>= 1) lmax = fmaxf(lmax, __shfl_xor(lmax, st, 64));
    if ((tid & 63) == 0) redw[tid >> 6] = lmax;
    __syncthreads();
    float mx = redw[0];
    #pragma unroll
    for (int i = 1; i < 16; ++i) mx = fmaxf(mx, redw[i]);

    float e = __expf(p[tid] - mx);
    float ls = e;
    #pragma unroll
    for (int st = 32; st > 0; st >>= 1) ls += __shfl_xor(ls, st, 64);
    __syncthreads();
    p[tid] = e;
    if ((tid & 63) == 0) redw[tid >> 6] = ls;
    __syncthreads();
    float ssum = 0.f;
    #pragma unroll
    for (int i = 0; i < 16; ++i) ssum += redw[i];
    float inv = 1.f / ssum;

    int d2 = (tid & 63) * 2, sb = tid >> 6;
    const unsigned short* Vb = KV + (size_t)b*Sq*2048 + 1024 + nh*DHq + d2;
    float a0 = 0.f, a1 = 0.f;
    for (int s = sb*64; s < sb*64 + 64; ++s) {
        unsigned int vv = *(const unsigned int*)(Vb + (size_t)s*2048);
        float pw = p[s];
        a0 += pw * bf2f(vv & 0xffffu);
        a1 += pw * bf2f(vv >> 16);
    }
    red2[sb*DHq + d2] = a0;
    red2[sb*DHq + d2 + 1] = a1;
    __syncthreads();
    if (tid < DHq) {
        float a = 0.f;
        #pragma unroll
        for (int i = 0; i < 16; ++i) a += red2[i*DHq + tid];
        o[b*Hq + nh*DHq + tid] = a * inv;
    }
}

extern "C" void kernel_launch(void* const* d_in, const int* in_sizes, int n_in,
                              void* d_out, int out_size, void* d_ws, size_t ws_size,
                              hipStream_t stream) {
    const float* x        = (const float*)d_in[0];
    const float* Wf       = (const float*)d_in[1];
    const float* bfv      = (const float*)d_in[2];
    const float* Wi       = (const float*)d_in[3];
    const float* biv      = (const float*)d_in[4];
    const float* Wh       = (const float*)d_in[5];
    const float* bhv      = (const float*)d_in[6];
    const float* in_proj_w= (const float*)d_in[7];
    const float* in_proj_b= (const float*)d_in[8];
    const float* out_w    = (const float*)d_in[9];
    const float* out_b    = (const float*)d_in[10];
    const float* fc_w     = (const float*)d_in[11];
    const float* fc_b     = (const float*)d_in[12];
    float* outp = (float*)d_out;

    // workspace carve (~160 MB)
    char* p = (char*)d_ws;
    auto alloc = [&](size_t bytes) -> void* {
        void* r = (void*)p; p += (bytes + 255) & ~(size_t)255; return r;
    };
    unsigned short* Wcat = (unsigned short*)alloc((size_t)Lq*3*HHq*2);  // 24 MB
    unsigned short* Wkv  = (unsigned short*)alloc((size_t)2048*Hq*2);   //  4 MB
    float*          Bias3= (float*)alloc((size_t)Lq*3*Hq*4);            // 48 KB
    unsigned short* actA = (unsigned short*)alloc((size_t)Mq*Hq*2);     // 32 MB
    unsigned short* actB = (unsigned short*)alloc((size_t)Mq*Hq*2);     // 32 MB
    unsigned short* FPg  = (unsigned short*)alloc((size_t)Mq*Hq*2);     // 32 MB
    unsigned short* ADDg = (unsigned short*)alloc((size_t)Mq*Hq*2);     // 32 MB (contiguous after FPg)
    float* Ps   = (float*)alloc((size_t)Bq*NCc*Hq*4);                   //  2 MB
    float* Asum = (float*)alloc((size_t)Bq*NCc*Hq*4);                   //  2 MB
    float* Hb   = (float*)alloc((size_t)Bq*NCc*Hq*4);                   //  2 MB
    unsigned short* KV = FPg;  // alias: 64 MB (FPg+ADDg), used only after layers done
    float* xl   = (float*)alloc((size_t)Bq*Hq*4);
    float* qbuf = (float*)alloc((size_t)Bq*Hq*4);
    float* obuf = (float*)alloc((size_t)Bq*Hq*4);
    float* rbuf = (float*)alloc((size_t)Bq*Hq*4);

    // --- conversions ---
    cvt_kernel<<<Mq*Hq/256, 256, 0, stream>>>(x, actA, Mq*Hq);
    cvtW_kernel<<<Lq*3*HHq/256, 256, 0, stream>>>(Wf, Wi, Wh, Wcat);
    cvt_kernel<<<2048*Hq/256, 256, 0, stream>>>(in_proj_w + (size_t)Hq*Hq, Wkv, 2048*Hq);
    bias3_kernel<<<(Lq*3*Hq)/256, 256, 0, stream>>>(bfv, biv, bhv, Bias3);

    // --- minLSTM layers ---
    unsigned short* cur = actA;
    unsigned short* nxt = actB;
    for (int l = 0; l < Lq; ++l) {
        gemm_gate_kernel<<<(Mq/256)*(Hq/128), 512, 0, stream>>>(
            cur, Wcat + (size_t)l*3*HHq, Bias3 + l*3*Hq, FPg, ADDg);
        scan_sum_kernel<<<Bq*NCc*2, 256, 0, stream>>>(FPg, ADDg, Ps, Asum);
        scan_base_kernel<<<Bq*Hq/256, 256, 0, stream>>>(Ps, Asum, Hb);
        scan_out_kernel<<<Bq*NCc*2, 256, 0, stream>>>(FPg, ADDg, Hb, nxt);
        unsigned short* t = cur; cur = nxt; nxt = t;
    }

    // --- attention (only last-position query matters) ---
    gemm_bt_kernel<<<(Mq/128)*(2048/128), 256, 0, stream>>>(
        cur, Wkv, in_proj_b + Hq, KV, 2048, Hq, 2048/128);
    xlast_kernel<<<Bq*Hq/256, 256, 0, stream>>>(cur, xl);
    gemv_kernel<<<dim3(Bq, Hq/4), 256, 0, stream>>>(in_proj_w, xl, in_proj_b, nullptr, qbuf, Hq);
    attn_kernel<<<Bq*NHq, 1024, 0, stream>>>(KV, qbuf, obuf);
    gemv_kernel<<<dim3(Bq, Hq/4), 256, 0, stream>>>(out_w, obuf, out_b, xl, rbuf, Hq);
    gemv_kernel<<<dim3(Bq, Oq/4), 256, 0, stream>>>(fc_w, rbuf, fc_b, nullptr, outp, Oq);
}